// Round 6
// baseline (101.926 us; speedup 1.0000x reference)
//
#include <hip/hip_runtime.h>

// MixtureOfExpertsNet: B=8388608 rows, E=4, H=16. f32 in/out.
// pred = sum_e(p_e*m_e*adj_e) / sum_e(p_e*m_e)   (softmax max-sub and /wsum cancel)
//   W2*relu(W1*x+b1) = s'_h*relu(x+r_h) + linear part folded into C1*x+K
//   gating weights pre-multiplied by log2e -> v_exp_f32 (exp2) directly.
//
// Round-6 theory: uniform weights were SGPR-allocated; ~156 dwords > ~102-SGPR
// budget -> in-loop s_load + lgkmcnt drains + v_mov bloat (1-SGPR-operand rule).
// Fix: fold weights ONCE PER THREAD into VGPRs (loads made to look divergent via
// an opaque zero VGPR offset), then a 16-row grid-stride loop whose body is pure
// VALU (f32x2 pk ops) + 1 coalesced load + 1 store. No prep dispatch.

typedef float f32x2 __attribute__((ext_vector_type(2)));
typedef float f32x4 __attribute__((ext_vector_type(4)));

#define ROWS 16

__global__ __launch_bounds__(256, 2) void moe_kernel(
    const f32x4* __restrict__ x,
    const float* __restrict__ Wg, const float* __restrict__ bg,
    const float* __restrict__ W1, const float* __restrict__ b1,
    const float* __restrict__ W2, const float* __restrict__ b2,
    float* __restrict__ out, int nthreads)
{
    int tid = blockIdx.x * blockDim.x + threadIdx.x;

    // Opaque zero in a VGPR: weight addresses derived from it look divergent,
    // so loads/results stay in VGPRs (never SGPR-allocated, no in-loop s_load).
    unsigned zoff;
    asm("v_mov_b32 %0, 0" : "=v"(zoff));
    const float* W1v = (const float*)((const char*)W1 + zoff);
    const float* b1v = (const float*)((const char*)b1 + zoff);
    const float* W2v = (const float*)((const char*)W2 + zoff);
    const float* Wgv = (const float*)((const char*)Wg + zoff);
    const float* bgv = (const float*)((const char*)bg + zoff);
    const float* b2v = (const float*)((const char*)b2 + zoff);

    // ---- per-thread weight fold (once, amortized over ROWS rows) ----
    f32x2 rp[32], sp[32];            // [e*8 + h2]
    float C1[4], K[4];
#pragma unroll
    for (int e = 0; e < 4; ++e) {
        float c1 = 0.0f, kk = b2v[e];
#pragma unroll
        for (int h2 = 0; h2 < 8; ++h2) {
            f32x2 w1 = *(const f32x2*)&W1v[e * 16 + 2 * h2];
            f32x2 bb = *(const f32x2*)&b1v[e * 16 + 2 * h2];
            f32x2 w2 = *(const f32x2*)&W2v[e * 16 + 2 * h2];
            f32x2 r, s;
#pragma unroll
            for (int q = 0; q < 2; ++q) {
                float w1q = w1[q], bbq = bb[q], w2q = w2[q];
                bool nz  = (w1q != 0.0f);
                bool neg = (w1q < 0.0f);
                float rq = nz ? bbq * __builtin_amdgcn_rcpf(w1q) : 0.0f;
                float pq = w1q * w2q;
                float sq = nz ? (neg ? -pq : pq) : 0.0f;
                c1 += neg ? pq : 0.0f;
                kk += neg ? pq * rq : (nz ? 0.0f : fmaxf(bbq, 0.0f) * w2q);
                r[q] = rq; s[q] = sq;
            }
            rp[e * 8 + h2] = r;
            sp[e * 8 + h2] = s;
        }
        C1[e] = c1; K[e] = kk;
    }

    const float L2E = 1.4426950408889634f;
    f32x2 wg[8];   // [j*2+p] = {Wg[2p][j], Wg[2p+1][j]} * log2e
    f32x2 bgp[2];
#pragma unroll
    for (int j = 0; j < 4; ++j)
#pragma unroll
        for (int p = 0; p < 2; ++p)
            wg[j * 2 + p] = (f32x2){Wgv[(2 * p + 0) * 4 + j] * L2E,
                                    Wgv[(2 * p + 1) * 4 + j] * L2E};
    bgp[0] = (f32x2){bgv[0] * L2E, bgv[1] * L2E};
    bgp[1] = (f32x2){bgv[2] * L2E, bgv[3] * L2E};

    // ---- grid-stride loop, manual distance-1 prefetch ----
    int idx = tid;
    f32x4 cur = x[idx];
#pragma unroll 1
    for (int r = 0; r < ROWS; ++r) {
        f32x4 nxt;
        if (r + 1 < ROWS) nxt = x[idx + nthreads];   // uniform branch; valid addr

        float xr[4] = {cur.x, cur.y, cur.z, cur.w};
        float xf[4]; bool ok[4];
#pragma unroll
        for (int e = 0; e < 4; ++e) {
            ok[e] = (xr[e] == xr[e]);
            xf[e] = ok[e] ? xr[e] : 0.0f;
        }

        f32x2 l01 = bgp[0], l23 = bgp[1];
#pragma unroll
        for (int j = 0; j < 4; ++j) {
            f32x2 xj = {xf[j], xf[j]};
            l01 = __builtin_elementwise_fma(xj, wg[j * 2 + 0], l01);
            l23 = __builtin_elementwise_fma(xj, wg[j * 2 + 1], l23);
        }
        float lg[4] = {l01.x, l01.y, l23.x, l23.y};

        float num = 0.0f, den = 0.0f;
#pragma unroll
        for (int e = 0; e < 4; ++e) {
            f32x2 xx = {xf[e], xf[e]};
            f32x2 a = {0.0f, 0.0f};
#pragma unroll
            for (int h2 = 0; h2 < 8; ++h2) {
                f32x2 u = xx + rp[e * 8 + h2];                       // v_pk_add_f32
                u = __builtin_elementwise_max(u, (f32x2){0.0f, 0.0f});
                a = __builtin_elementwise_fma(u, sp[e * 8 + h2], a); // v_pk_fma_f32
            }
            float adj = fmaxf(a.x + a.y + fmaf(xf[e], C1[e], K[e]), 0.0f);
            float p = ok[e] ? __builtin_amdgcn_exp2f(lg[e]) : 0.0f;
            den += p;
            num = fmaf(p, adj, num);
        }
        // den==0 only when all experts masked: num=0 -> 0*inf = NaN (matches ref)
        out[idx] = num * __builtin_amdgcn_rcpf(den);

        idx += nthreads;
        cur = nxt;
    }
}

extern "C" void kernel_launch(void* const* d_in, const int* in_sizes, int n_in,
                              void* d_out, int out_size, void* d_ws, size_t ws_size,
                              hipStream_t stream) {
    const f32x4* x  = (const f32x4*)d_in[0];
    const float* Wg = (const float*)d_in[1];
    const float* bg = (const float*)d_in[2];
    const float* W1 = (const float*)d_in[3];
    const float* b1 = (const float*)d_in[4];
    const float* W2 = (const float*)d_in[5];
    const float* b2 = (const float*)d_in[6];
    float* out = (float*)d_out;

    int B = in_sizes[0] / 4;          // 8388608 rows
    int nthreads = B / ROWS;          // 524288
    int blocks = nthreads / 256;      // 2048
    moe_kernel<<<blocks, 256, 0, stream>>>(x, Wg, bg, W1, b1, W2, b2, out, nthreads);
}

// Round 7
// 59.330 us; speedup vs baseline: 1.7179x; 1.7179x over previous
//
#include <hip/hip_runtime.h>

// MixtureOfExpertsNet: B=8388608 rows, E=4, H=16. f32 in/out.
// pred = sum_e(p_e*m_e*adj_e) / sum_e(p_e*m_e)   (softmax max-sub and /wsum cancel)
//   W2*relu(W1*x+b1) = s'_h*relu(x+r_h) + linear part folded into C1*x+K
//   gating weights pre-multiplied by log2e -> v_exp_f32 (exp2) directly.
//   masked experts: lg = -inf -> exp2 = 0 exactly (no mask registers).
//
// Round-7 theory: uniform weights >102 SGPRs -> in-loop s_load+lgkmcnt drains
// (rounds 1-5); VGPR-forcing without residency/occupancy fails (round 6:
// VGPR=104 < weight set, Occ 19%). Fix: per-block cooperative fold into LDS
// (ds_read can't scalarize -> guaranteed VGPR, broadcast is conflict-free),
// experts-outer register tiling: each expert's 32 weight floats resident for
// 8 rows. Body = pure VALU (f32x2 pk ops), no in-loop SMEM/VMEM.

typedef float f32x2 __attribute__((ext_vector_type(2)));
typedef float f32x4 __attribute__((ext_vector_type(4)));

#define RPT 8

__global__ __launch_bounds__(256, 3) void moe_kernel(
    const f32x4* __restrict__ x,
    const float* __restrict__ Wg, const float* __restrict__ bg,
    const float* __restrict__ W1, const float* __restrict__ b1,
    const float* __restrict__ W2, const float* __restrict__ b2,
    float* __restrict__ out)
{
    // LDS layout (floats): [0..63] r (e*16+h), [64..127] s' (e*16+h),
    // [128..159] per-expert consts: e*8 + {C1, K, bg*L2E, wg0..wg3 *L2E, pad}
    __shared__ float lds[160];
    const int t = threadIdx.x;
    const int base = blockIdx.x * (256 * RPT) + t;

    // ---- issue all 8 row loads first; latency hides under fold + barrier ----
    f32x4 xv[RPT];
#pragma unroll
    for (int k = 0; k < RPT; ++k)
        xv[k] = x[base + k * 256];

    // ---- cooperative weight fold into LDS (redundant per block, tiny) ----
    const float L2E = 1.4426950408889634f;
    if (t < 64) {
        int e = t >> 4, h = t & 15;
        float w1 = W1[e * 16 + h], bb = b1[e * 16 + h], w2 = W2[e * 16 + h];
        bool nz = (w1 != 0.0f), neg = (w1 < 0.0f);
        float r = nz ? bb * __builtin_amdgcn_rcpf(w1) : 0.0f;
        float pq = w1 * w2;
        float s = nz ? (neg ? -pq : pq) : 0.0f;
        lds[e * 16 + h] = r;
        lds[64 + e * 16 + h] = s;
    } else if (t < 68) {
        int e = t - 64;
        float c1 = 0.0f, kk = b2[e];
        for (int h = 0; h < 16; ++h) {
            float w1 = W1[e * 16 + h], bb = b1[e * 16 + h], w2 = W2[e * 16 + h];
            bool nz = (w1 != 0.0f), neg = (w1 < 0.0f);
            float pq = w1 * w2;
            float rq = nz ? bb * __builtin_amdgcn_rcpf(w1) : 0.0f;
            c1 += neg ? pq : 0.0f;
            kk += neg ? pq * rq : (nz ? 0.0f : fmaxf(bb, 0.0f) * w2);
        }
        lds[128 + e * 8 + 0] = c1;
        lds[128 + e * 8 + 1] = kk;
    } else if (t < 72) {
        int e = t - 68;
        lds[128 + e * 8 + 2] = bg[e] * L2E;
        lds[128 + e * 8 + 7] = 0.0f;
    } else if (t < 88) {
        int idx = t - 72, e = idx >> 2, j = idx & 3;
        lds[128 + e * 8 + 3 + j] = Wg[e * 4 + j] * L2E;
    }
    __syncthreads();

    // ---- pre-pass: xf + mask-folded logits (lg = ok ? logit : -inf) ----
    f32x4 ga[4], gb[4];   // {C1,K,bgl,wg0}, {wg1,wg2,wg3,pad} per expert
#pragma unroll
    for (int e = 0; e < 4; ++e) {
        ga[e] = *(const f32x4*)&lds[128 + e * 8];
        gb[e] = *(const f32x4*)&lds[128 + e * 8 + 4];
    }

    float xf[RPT][4], lg[RPT][4];
#pragma unroll
    for (int k = 0; k < RPT; ++k) {
        float xr[4] = {xv[k].x, xv[k].y, xv[k].z, xv[k].w};
        bool ok[4];
#pragma unroll
        for (int e = 0; e < 4; ++e) {
            ok[e] = (xr[e] == xr[e]);               // !isnan
            xf[k][e] = ok[e] ? xr[e] : 0.0f;
        }
#pragma unroll
        for (int e = 0; e < 4; ++e) {
            float l = fmaf(xf[k][0], ga[e].w,
                      fmaf(xf[k][1], gb[e].x,
                      fmaf(xf[k][2], gb[e].y,
                      fmaf(xf[k][3], gb[e].z, ga[e].z))));
            lg[k][e] = ok[e] ? l : -__builtin_inff();
        }
    }

    // ---- experts-outer: expert weights register-resident across 8 rows ----
    float num[RPT], den[RPT];
#pragma unroll
    for (int k = 0; k < RPT; ++k) { num[k] = 0.0f; den[k] = 0.0f; }

#pragma unroll
    for (int e = 0; e < 4; ++e) {
        const f32x4* lr = (const f32x4*)&lds[e * 16];
        const f32x4* ls = (const f32x4*)&lds[64 + e * 16];
        f32x2 rp[8], sp[8];
#pragma unroll
        for (int q = 0; q < 4; ++q) {
            f32x4 rv = lr[q], sv = ls[q];
            rp[2 * q + 0] = (f32x2){rv.x, rv.y};
            rp[2 * q + 1] = (f32x2){rv.z, rv.w};
            sp[2 * q + 0] = (f32x2){sv.x, sv.y};
            sp[2 * q + 1] = (f32x2){sv.z, sv.w};
        }
        f32x2 ck = *(const f32x2*)&lds[128 + e * 8];   // {C1, K}

#pragma unroll
        for (int k = 0; k < RPT; ++k) {
            float xe = xf[k][e];
            f32x2 xx = {xe, xe};
            f32x2 a = {0.0f, 0.0f};
#pragma unroll
            for (int h2 = 0; h2 < 8; ++h2) {
                f32x2 u = xx + rp[h2];                            // v_pk_add_f32
                u = __builtin_elementwise_max(u, (f32x2){0.0f, 0.0f});
                a = __builtin_elementwise_fma(u, sp[h2], a);      // v_pk_fma_f32
            }
            float adj = fmaxf(a.x + a.y + fmaf(xe, ck.x, ck.y), 0.0f);
            float p = __builtin_amdgcn_exp2f(lg[k][e]);           // 0 if masked
            den[k] += p;
            num[k] = fmaf(p, adj, num[k]);
        }
    }

    // den==0 only when all experts masked: num=0 -> 0*inf = NaN (matches ref)
#pragma unroll
    for (int k = 0; k < RPT; ++k)
        out[base + k * 256] = num[k] * __builtin_amdgcn_rcpf(den[k]);
}

extern "C" void kernel_launch(void* const* d_in, const int* in_sizes, int n_in,
                              void* d_out, int out_size, void* d_ws, size_t ws_size,
                              hipStream_t stream) {
    const f32x4* x  = (const f32x4*)d_in[0];
    const float* Wg = (const float*)d_in[1];
    const float* bg = (const float*)d_in[2];
    const float* W1 = (const float*)d_in[3];
    const float* b1 = (const float*)d_in[4];
    const float* W2 = (const float*)d_in[5];
    const float* b2 = (const float*)d_in[6];
    float* out = (float*)d_out;

    int B = in_sizes[0] / 4;            // 8388608 rows
    int blocks = B / (256 * RPT);       // 4096
    moe_kernel<<<blocks, 256, 0, stream>>>(x, Wg, bg, W1, b1, W2, b2, out);
}